// Round 8
// baseline (113.774 us; speedup 1.0000x reference)
//
#include <hip/hip_runtime.h>
#include <hip/hip_bf16.h>

// Dilated-mask attention, B=2 H=16 S=2048 D=64, dilation=2 — single fused kernel.
// mask[i,j]=1 iff same parity; masked scores exactly 0 -> flash attn over
// same-parity keys with fixed m=0, Z = l + 1024, out += Vsum_otherparity.
//
// R8: R7's direct-P inner loop (st = K·Q^T exits QK in the 16x16x16 B-operand
// layout; exp in regs feeds PV directly, O^T += V^T(A)·P(B); no P LDS trip)
// at R5's occupancy: 512-thread blocks, 8 waves x 16 queries, grid 512 =
// 2 blocks/CU = 16 waves/CU. Staging state 24 floats/thread fits the
// (512,4) 128-VGPR cap; frags read just-in-time to cap live pressure.

#define B_   2
#define H_   16
#define S_   2048
#define D_   64
#define SP_  1024
#define BQ   128
#define BK   64
#define NKT  (SP_ / BK)
#define NW   8          // waves per block; each owns 16 queries

// Q pre-scale: 1/sqrt(64) * log2(e)  ->  p = exp2(QK') = exp(QK/8)
#define QSCALE 0.180336884f

#if __has_builtin(__builtin_amdgcn_exp2f)
#define EXP2(x) __builtin_amdgcn_exp2f(x)
#else
#define EXP2(x) exp2f(x)
#endif

typedef __bf16 bf16x8 __attribute__((ext_vector_type(8)));
typedef __bf16 bf16x4 __attribute__((ext_vector_type(4)));
typedef float  f32x4  __attribute__((ext_vector_type(4)));
typedef short  s16x4  __attribute__((ext_vector_type(4)));

static __device__ __forceinline__ f32x4 mfma16(bf16x4 a, bf16x4 b, f32x4 c) {
    return __builtin_amdgcn_mfma_f32_16x16x16bf16_1k(
        __builtin_bit_cast(s16x4, a), __builtin_bit_cast(s16x4, b), c, 0, 0, 0);
}

// XOR-swizzled element offset inside a 64-elem (128 B) row: 16 B chunk c8 of
// row r lands at chunk c8^(r&7). Staging b128 writes, K b128 frag reads, and
// V^T b64 A-frag reads all <=2-way (free).
#define KSW(r, c8) ((((c8) ^ ((r) & 7)) << 3))

__global__ __launch_bounds__(512, 4) void attn_kernel(const float* __restrict__ Q,
                                                      const float* __restrict__ K,
                                                      const float* __restrict__ V,
                                                      float* __restrict__ out) {
    const int bh  = blockIdx.x;
    const int par = blockIdx.y;
    const int qt  = blockIdx.z;
    const int tid  = threadIdx.x;
    const int lane = tid & 63;
    const int wave = tid >> 6;       // wave w owns query rows [16w, 16w+16)
    const int l15  = lane & 15;
    const int quad = lane >> 4;

    // arena: [0,16K) kbuf[2][64][64] bf16, [16K,32K) vbuf[2][64][64] bf16 (V^T),
    // epilogue reuses [0,34816) as 8 per-wave f32 [16 q][68 d] transpose tiles;
    // vred lives above at [34816, 36864).
    __shared__ __align__(16) char arena[36864];
    __bf16 (*kbuf)[BK][64] = (__bf16 (*)[BK][64])arena;
    __bf16 (*vbuf)[D_][64] = (__bf16 (*)[D_][64])(arena + 16384);
    float  (*vred)[64]     = (float  (*)[64])(arena + 34816);

    const size_t base = (size_t)bh * S_ * D_;
    const float* Qb = Q + base;
    const float* Kb = K + base;
    const float* Vb = V + base;
    const int vofs = (par == 0) ? D_ : -D_;            // opp-parity row offset

    // ---- Q as QK B-operand fragments (st = K·Q^T): B[n=query l15][k=d]
    bf16x8 qf[2];
    {
        const int qrow = qt * BQ + wave * 16 + l15;
        const float* qsrc = Qb + (size_t)(par + 2 * qrow) * D_ + quad * 8;
        #pragma unroll
        for (int ks = 0; ks < 2; ++ks) {
            const float4 a = *(const float4*)(qsrc + ks * 32);
            const float4 b = *(const float4*)(qsrc + ks * 32 + 4);
            bf16x8 w;
            w[0] = (__bf16)(a.x * QSCALE); w[1] = (__bf16)(a.y * QSCALE);
            w[2] = (__bf16)(a.z * QSCALE); w[3] = (__bf16)(a.w * QSCALE);
            w[4] = (__bf16)(b.x * QSCALE); w[5] = (__bf16)(b.y * QSCALE);
            w[6] = (__bf16)(b.z * QSCALE); w[7] = (__bf16)(b.w * QSCALE);
            qf[ks] = w;
        }
    }

    // staging decomposition (512 threads):
    //   K: row tid>>3 (0..63), 16B chunk tid&7 -> 2 float4 loads, 1 b128 write
    //   V: column `lane`, key-chunk `wave` (keys 8w..8w+7) -> 8+8 scalar loads
    const int kr  = tid >> 3;
    const int kc8 = tid & 7;

    float4 pka, pkb;                 // K prefetch
    float  pv[8], pvo[8];            // V / opp-V prefetch

    auto issue_loads = [&](int kt) {
        const float* ksrc = Kb + (size_t)(par + 2 * (kt * BK + kr)) * D_ + kc8 * 8;
        pka = *(const float4*)ksrc;
        pkb = *(const float4*)(ksrc + 4);
        const float* vsrc = Vb + (size_t)(par + 2 * (kt * BK + wave * 8)) * D_ + lane;
        #pragma unroll
        for (int j = 0; j < 8; ++j) {
            pv [j] = vsrc[(size_t)(2 * j) * D_];
            pvo[j] = vsrc[(size_t)(2 * j) * D_ + vofs];
        }
    };

    float vo = 0.f;                  // opp-parity Vsum partial, column d = lane
    auto stage = [&](int buf) {
        bf16x8 w;
        w[0] = (__bf16)pka.x; w[1] = (__bf16)pka.y;
        w[2] = (__bf16)pka.z; w[3] = (__bf16)pka.w;
        w[4] = (__bf16)pkb.x; w[5] = (__bf16)pkb.y;
        w[6] = (__bf16)pkb.z; w[7] = (__bf16)pkb.w;
        *(bf16x8*)&kbuf[buf][kr][KSW(kr, kc8)] = w;
        bf16x8 wv;
        #pragma unroll
        for (int j = 0; j < 8; ++j) wv[j] = (__bf16)pv[j];
        *(bf16x8*)&vbuf[buf][lane][KSW(lane, wave)] = wv;
        vo += ((pvo[0] + pvo[1]) + (pvo[2] + pvo[3]))
            + ((pvo[4] + pvo[5]) + (pvo[6] + pvo[7]));
    };

    issue_loads(0);
    stage(0);
    __syncthreads();

    // O^T accumulators: C[m=d=quad*4+r (+16dt)][n=query=l15]
    f32x4 acc[4];
    #pragma unroll
    for (int dt = 0; dt < 4; ++dt) acc[dt] = (f32x4){0.f, 0.f, 0.f, 0.f};
    float l_acc = 0.f;               // per-lane partial Z for query l15

    for (int kt = 0; kt < NKT; ++kt) {
        const int cur = kt & 1;
        const bool pf = (kt + 1 < NKT);

        if (pf) issue_loads(kt + 1);   // latency overlaps compute below

        const __bf16 (*kb)[64] = kbuf[cur];
        const __bf16 (*vb)[64] = vbuf[cur];

        // ---- st = K·Q^T (A-frags read just-in-time, live 1 at a time)
        f32x4 st[4];
        #pragma unroll
        for (int kt4 = 0; kt4 < 4; ++kt4) st[kt4] = (f32x4){0.f, 0.f, 0.f, 0.f};
        #pragma unroll
        for (int ks = 0; ks < 2; ++ks)
            #pragma unroll
            for (int kt4 = 0; kt4 < 4; ++kt4) {
                const int R = kt4 * 16 + l15;
                const bf16x8 a = *(const bf16x8*)&kb[R][KSW(R, ks * 4 + quad)];
                st[kt4] = __builtin_amdgcn_mfma_f32_16x16x32_bf16(a, qf[ks], st[kt4], 0, 0, 0);
            }

        // ---- p = exp2(st) is directly the 16x16x16 B-operand; PV in place.
        //      V^T A-frags (b64) read just-in-time per (kt4,dt).
        #pragma unroll
        for (int kt4 = 0; kt4 < 4; ++kt4) {
            const float p0 = EXP2(st[kt4][0]);
            const float p1 = EXP2(st[kt4][1]);
            const float p2 = EXP2(st[kt4][2]);
            const float p3 = EXP2(st[kt4][3]);
            l_acc += (p0 + p1) + (p2 + p3);
            bf16x4 pb;
            pb[0] = (__bf16)p0; pb[1] = (__bf16)p1;
            pb[2] = (__bf16)p2; pb[3] = (__bf16)p3;
            #pragma unroll
            for (int dt = 0; dt < 4; ++dt) {
                const int R = dt * 16 + l15;
                const int ch = (kt4 * 2 + (quad >> 1)) ^ (R & 7);
                const bf16x4 va = *(const bf16x4*)&vb[R][ch * 8 + (quad & 1) * 4];
                acc[dt] = mfma16(va, pb, acc[dt]);
            }
        }

        if (pf) stage(1 - cur);
        __syncthreads();
    }

    // ---- cross-wave reduction of opp-parity Vsum (vred disjoint from tw tiles)
    vred[wave][lane] = vo;
    __syncthreads();

    f32x4 vs4[4];
    #pragma unroll
    for (int dt = 0; dt < 4; ++dt) {
        f32x4 s = (f32x4){0.f, 0.f, 0.f, 0.f};
        #pragma unroll
        for (int w = 0; w < NW; ++w)
            s += *(const f32x4*)&vred[w][dt * 16 + quad * 4];
        vs4[dt] = s;
    }
    // Z per query l15 (fold quads), applied per-lane to O^T columns
    float Z = l_acc;
    Z += __shfl_xor(Z, 16);
    Z += __shfl_xor(Z, 32);
    const float rz = 1.0f / (Z + 1024.0f);

    // ---- epilogue transpose: per-wave private f32 tile [16 q][68 d]
    float* tw = (float*)arena + wave * (16 * 68);
    #pragma unroll
    for (int dt = 0; dt < 4; ++dt) {
        const f32x4 o = (acc[dt] + vs4[dt]) * rz;
        *(f32x4*)&tw[l15 * 68 + dt * 16 + quad * 4] = o;
    }
    // per-wave private + in-order DS pipe: no barrier needed
    #pragma unroll
    for (int i = 0; i < 4; ++i) {
        const int q = i * 4 + quad;
        const f32x4 ov = *(const f32x4*)&tw[q * 68 + l15 * 4];
        const int qg = par + 2 * (qt * BQ + wave * 16 + q);
        *(f32x4*)&out[base + (size_t)qg * D_ + l15 * 4] = ov;
    }
}

extern "C" void kernel_launch(void* const* d_in, const int* in_sizes, int n_in,
                              void* d_out, int out_size, void* d_ws, size_t ws_size,
                              hipStream_t stream) {
    const float* Q = (const float*)d_in[0];
    const float* K = (const float*)d_in[1];
    const float* V = (const float*)d_in[2];
    float* out = (float*)d_out;
    attn_kernel<<<dim3(B_ * H_, 2, SP_ / BQ), dim3(512), 0, stream>>>(Q, K, V, out);
}